// Round 9
// baseline (923.136 us; speedup 1.0000x reference)
//
#include <hip/hip_runtime.h>
#include <stdint.h>

typedef __attribute__((ext_vector_type(8))) short short8;
typedef __attribute__((ext_vector_type(4))) short short4v;
typedef __attribute__((ext_vector_type(4))) float floatx4;

__device__ __forceinline__ unsigned short f2bf(float x) {
  unsigned int u = __float_as_uint(x);
  u += 0x7fffu + ((u >> 16) & 1u);   // RNE
  return (unsigned short)(u >> 16);
}
__device__ __forceinline__ float bf2f(unsigned short b) {
  return __uint_as_float(((unsigned int)b) << 16);
}
__device__ __forceinline__ int sw3(int r) { return (r & 7) ^ (((r >> 3) & 1) * 3); }

// ---- unified prologue: weight frags + h bf16 table ----
// W1F/W2F B-frag layout: u=((k32*256+n)*4+kq)*8+j  holds W[k32*32+kq*8+j][n]
// W3F (N padded 2->16): u=(k32*64+L)*8+j holds W3[k32*32+(L>>4)*8+j][L&15] or 0
__global__ void prep_kernel(const float* __restrict__ h, const float* __restrict__ W1,
                            const float* __restrict__ W2, const float* __restrict__ W3,
                            unsigned short* __restrict__ HBF, unsigned short* __restrict__ W1F,
                            unsigned short* __restrict__ W2F, unsigned short* __restrict__ W3F,
                            int nh4) {
  const int t = threadIdx.x;
  int b = blockIdx.x;
  if (b < 512) {
    int u = b * 256 + t;
    int j = u & 7, kq = (u >> 3) & 3, n = (u >> 5) & 255, k32 = u >> 13;
    W1F[u] = f2bf(W1[(k32 * 32 + kq * 8 + j) * 256 + n]);
    return;
  }
  b -= 512;
  if (b < 256) {
    int u = b * 256 + t;
    int j = u & 7, kq = (u >> 3) & 3, n = (u >> 5) & 255, k32 = u >> 13;
    W2F[u] = f2bf(W2[(k32 * 32 + kq * 8 + j) * 256 + n]);
    return;
  }
  b -= 256;
  if (b < 16) {
    int u = b * 256 + t;
    int j = u & 7, L = (u >> 3) & 63, k32 = u >> 9;
    int n = L & 15, kq = L >> 4;
    W3F[u] = (n < 2) ? f2bf(W3[(k32 * 32 + kq * 8 + j) * 2 + n]) : (unsigned short)0;
    return;
  }
  b -= 16;
  int u = b * 256 + t;
  if (u < nh4) {
    float4 v = ((const float4*)h)[u];
    short4v s;
    s[0] = (short)f2bf(v.x); s[1] = (short)f2bf(v.y);
    s[2] = (short)f2bf(v.z); s[3] = (short)f2bf(v.w);
    ((short4v*)HBF)[u] = s;
  }
}

// ---- persistent pipelined kernel (plain-load gather, reg staging dies mid-tile) ----
// 512 threads (8 waves, N=32 cols each), 1 block/CU.
// LDS: AB[2] A-tiles, pair-row = 64 chunks x 16 B, row stride 1040 B (uniform bank
// quads for b128 reads/writes); X (32 KB) + X2 (32 KB) overlay AB[cur]. iobuf 1 KB.
// Pipeline per tile T: prime B1-ring(8) -> issue 8 gather loads g for T+1 (plain
// VGPR loads, 2x512B segments) -> L1 k-loop (B refills after g in vmcnt queue, so
// waits give g the whole L1 to drain) -> ds_write g -> epilogues/L2/L3.
__global__ __launch_bounds__(512, 2)
void edge_mlp5(const unsigned short* __restrict__ hbf,
               const int* __restrict__ dst,
               const int* __restrict__ src,
               const unsigned short* __restrict__ W1F,
               const unsigned short* __restrict__ W2F,
               const unsigned short* __restrict__ W3F,
               float* __restrict__ out, int ntiles) {
  __shared__ unsigned char AB[2][66560];
  __shared__ int iobuf[2][128];

  const int t = threadIdx.x, lane = t & 63, w = t >> 6;
  const int lq = lane >> 4, lm = lane & 15;
  const int bid = blockIdx.x, stride = gridDim.x;
  const int nIter = (ntiles - bid + stride - 1) / stride;
  const int last = nIter - 1;

  const short8* B1 = (const short8*)W1F;
  const short8* B2 = (const short8*)W2F;
  const short8* B3 = (const short8*)W3F;

  if (t < 128) {
    const int* p = (t < 64) ? dst : src;
    int i0 = t & 63;
    iobuf[0][t] = p[bid * 64 + i0];
    if (last >= 1) iobuf[1][t] = p[(bid + stride) * 64 + i0];
  }
  __syncthreads();

  // ---- tile-0 gather (synchronous, reg-staged)
  {
    short8 g[8];
#pragma unroll
    for (int u = 0; u < 8; ++u) {
      int r = w * 8 + u;
      int node = (lane < 32) ? iobuf[0][r] : iobuf[0][64 + r];
      g[u] = ((const short8*)hbf)[(size_t)node * 32 + (lane & 31)];
    }
#pragma unroll
    for (int u = 0; u < 8; ++u)
      *(short8*)&AB[0][(w * 8 + u) * 1040 + lane * 16] = g[u];
  }
  __syncthreads();

  for (int T = 0; T < nIter; ++T) {
    const int cur = T & 1, nxt = cur ^ 1;
    const int m0 = (bid + T * stride) * 64;
    unsigned short* X  = (unsigned short*)&AB[cur][0];
    unsigned short* X2 = X + 64 * 256;
    const bool pre = T < last;

    // ---- prime B1 ring depth 8 (issued BEFORE g: early k-steps never fence g)
    short8 bq[8][2];
#pragma unroll
    for (int s = 0; s < 8; ++s)
#pragma unroll
      for (int j = 0; j < 2; ++j)
        bq[s][j] = B1[(s * 256 + w * 32 + j * 16 + lm) * 4 + lq];

    // ---- issue gather(T+1): 8 plain loads, 2x512B coalesced segments each
    short8 g[8];
    if (pre) {
#pragma unroll
      for (int u = 0; u < 8; ++u) {
        int r = w * 8 + u;
        int node = (lane < 32) ? iobuf[nxt][r] : iobuf[nxt][64 + r];
        g[u] = ((const short8*)hbf)[(size_t)node * 32 + (lane & 31)];
      }
    }

    floatx4 acc[4][2];
#pragma unroll
    for (int i = 0; i < 4; ++i)
#pragma unroll
      for (int j = 0; j < 2; ++j) acc[i][j] = (floatx4)(0.0f);

    // ---- Layer 1: K=512, 16 k-steps; refills (slots 8..15) issued after g
#pragma unroll
    for (int s = 0; s < 16; ++s) {
#pragma unroll
      for (int i = 0; i < 4; ++i) {
        int r = i * 16 + lm;
        short8 af = *(const short8*)&AB[cur][r * 1040 + (s * 4 + lq) * 16];
        acc[i][0] = __builtin_amdgcn_mfma_f32_16x16x32_bf16(af, bq[s & 7][0], acc[i][0], 0, 0, 0);
        acc[i][1] = __builtin_amdgcn_mfma_f32_16x16x32_bf16(af, bq[s & 7][1], acc[i][1], 0, 0, 0);
      }
      if (s < 8)
#pragma unroll
        for (int j = 0; j < 2; ++j)
          bq[s][j] = B1[((s + 8) * 256 + w * 32 + j * 16 + lm) * 4 + lq];
    }

    // ---- idx(T+2) prefetch into reg
    int idxv = 0;
    const bool doidx = (T + 2 <= last) && (t < 128);
    if (doidx) {
      const int* p = (t < 64) ? dst : src;
      idxv = p[(bid + (T + 2) * stride) * 64 + (t & 63)];
    }

    // ---- commit g to AB[nxt]; vmcnt drain here was covered by the L1 phase
    if (pre) {
#pragma unroll
      for (int u = 0; u < 8; ++u)
        *(short8*)&AB[nxt][(w * 8 + u) * 1040 + lane * 16] = g[u];
    }
    __syncthreads();   // all A[cur] reads done; A[nxt] staged

    // ---- Epilogue 1: relu -> X (C/D: col=lane&15, row=quad*4+reg)
#pragma unroll
    for (int i = 0; i < 4; ++i) {
      int row0 = i * 16 + lq * 4;
#pragma unroll
      for (int j = 0; j < 2; ++j) {
        int col = w * 32 + j * 16 + lm, c8 = col >> 3, ce = col & 7;
#pragma unroll
        for (int rg = 0; rg < 4; ++rg) {
          int row = row0 + rg;
          float v = acc[i][j][rg];
          v = v > 0.0f ? v : 0.0f;
          X[row * 256 + (((c8 ^ sw3(row)) << 3) | ce)] = f2bf(v);
        }
      }
    }
    if (doidx) iobuf[cur][t] = idxv;   // (T+2)&1 == cur
#pragma unroll
    for (int i = 0; i < 4; ++i)
#pragma unroll
      for (int j = 0; j < 2; ++j) acc[i][j] = (floatx4)(0.0f);
    __syncthreads();   // X visible

    // ---- Layer 2: K=256, 8 k-steps; all B2 primed up-front (reuses bq regs)
#pragma unroll
    for (int s = 0; s < 8; ++s)
#pragma unroll
      for (int j = 0; j < 2; ++j)
        bq[s][j] = B2[(s * 256 + w * 32 + j * 16 + lm) * 4 + lq];
#pragma unroll
    for (int s = 0; s < 8; ++s) {
#pragma unroll
      for (int i = 0; i < 4; ++i) {
        int r = i * 16 + lm;
        short8 af = *(const short8*)&X[r * 256 + (((s * 4 + lq) ^ sw3(r)) << 3)];
        acc[i][0] = __builtin_amdgcn_mfma_f32_16x16x32_bf16(af, bq[s][0], acc[i][0], 0, 0, 0);
        acc[i][1] = __builtin_amdgcn_mfma_f32_16x16x32_bf16(af, bq[s][1], acc[i][1], 0, 0, 0);
      }
    }

    // ---- Epilogue 2: relu -> X2 (disjoint from X: no barrier needed before)
#pragma unroll
    for (int i = 0; i < 4; ++i) {
      int row0 = i * 16 + lq * 4;
#pragma unroll
      for (int j = 0; j < 2; ++j) {
        int col = w * 32 + j * 16 + lm, c8 = col >> 3, ce = col & 7;
#pragma unroll
        for (int rg = 0; rg < 4; ++rg) {
          int row = row0 + rg;
          float v = acc[i][j][rg];
          v = v > 0.0f ? v : 0.0f;
          X2[row * 256 + (((c8 ^ sw3(row)) << 3) | ce)] = f2bf(v);
        }
      }
    }
    __syncthreads();   // X2 visible

    // ---- Layer 3 (waves 0..3): X2 @ W3 via MFMA, N padded to 16
    if (w < 4) {
      floatx4 a3 = (floatx4)(0.0f);
#pragma unroll
      for (int s = 0; s < 8; ++s) {
        short8 b3 = B3[s * 64 + lane];
        int r = w * 16 + lm;
        short8 af = *(const short8*)&X2[r * 256 + (((s * 4 + lq) ^ sw3(r)) << 3)];
        a3 = __builtin_amdgcn_mfma_f32_16x16x32_bf16(af, b3, a3, 0, 0, 0);
      }
      if (lm < 2) {
#pragma unroll
        for (int rg = 0; rg < 4; ++rg)
          out[(m0 + w * 16 + lq * 4 + rg) * 2 + lm] = a3[rg];
      }
    }
    __syncthreads();   // X/X2 (in AB[cur]) dead before T+1's gather writes AB[cur]
  }
}

// ---- legacy weight-frag kernel (fallback path only) ----
__global__ void wfrag_kernel(const float* __restrict__ W,
                             unsigned short* __restrict__ out, int total) {
  int u = blockIdx.x * 256 + threadIdx.x;
  if (u >= total) return;
  int j = u & 7, kq = (u >> 3) & 3, n = (u >> 5) & 255, k32 = u >> 13;
  out[u] = f2bf(W[(k32 * 32 + kq * 8 + j) * 256 + n]);
}

// ---- fp32-gather fallback (tiny workspace) ----
__global__ __launch_bounds__(256, 2)
void edge_mlp_fb(const float* __restrict__ h,
                 const int* __restrict__ dst,
                 const int* __restrict__ src,
                 const unsigned short* __restrict__ W1F,
                 const unsigned short* __restrict__ W2F,
                 const float* __restrict__ W3,
                 float* __restrict__ out) {
  __shared__ unsigned short A[64 * 512];
  __shared__ float w3s[512];
  __shared__ int ioff[128];
  unsigned short* X = A;
  const int t = threadIdx.x, lane = t & 63, w = t >> 6;
  const int lq = lane >> 4, lm = lane & 15;
  const int m0 = blockIdx.x * 64;
  if (t < 64) ioff[t] = dst[m0 + t];
  else if (t < 128) ioff[t] = src[m0 + t - 64];
  w3s[t] = W3[t];
  w3s[t + 256] = W3[t + 256];
  __syncthreads();
  {
    const int c = lane, half = (c >= 32) ? 64 : 0, cc = c & 31;
#pragma unroll
    for (int it = 0; it < 16; ++it) {
      int r = it * 4 + w;
      int node = ioff[half + r];
      const float4* h4 = (const float4*)h;
      float4 v0 = h4[node * 64 + cc * 2], v1 = h4[node * 64 + cc * 2 + 1];
      short8 v;
      v[0] = (short)f2bf(v0.x); v[1] = (short)f2bf(v0.y);
      v[2] = (short)f2bf(v0.z); v[3] = (short)f2bf(v0.w);
      v[4] = (short)f2bf(v1.x); v[5] = (short)f2bf(v1.y);
      v[6] = (short)f2bf(v1.z); v[7] = (short)f2bf(v1.w);
      *(short8*)&A[r * 512 + ((c ^ (r & 7)) << 3)] = v;
    }
  }
  floatx4 acc[4][4];
#pragma unroll
  for (int i = 0; i < 4; ++i)
#pragma unroll
    for (int j = 0; j < 4; ++j) acc[i][j] = (floatx4)(0.0f);
  __syncthreads();
  const short8* B1 = (const short8*)W1F;
  const short8* B2 = (const short8*)W2F;
#pragma unroll
  for (int k32 = 0; k32 < 16; ++k32) {
    short8 b[4], af[4];
#pragma unroll
    for (int jt = 0; jt < 4; ++jt)
      b[jt] = B1[(k32 * 256 + w * 64 + jt * 16 + lm) * 4 + lq];
#pragma unroll
    for (int i = 0; i < 4; ++i) {
      int r = i * 16 + lm, c = k32 * 4 + lq;
      af[i] = *(const short8*)&A[r * 512 + ((c ^ (r & 7)) << 3)];
    }
#pragma unroll
    for (int i = 0; i < 4; ++i)
#pragma unroll
      for (int j = 0; j < 4; ++j)
        acc[i][j] = __builtin_amdgcn_mfma_f32_16x16x32_bf16(af[i], b[j], acc[i][j], 0, 0, 0);
  }
  __syncthreads();
#pragma unroll
  for (int i = 0; i < 4; ++i) {
    int row0 = i * 16 + lq * 4;
#pragma unroll
    for (int j = 0; j < 4; ++j) {
      int col = w * 64 + j * 16 + lm, c8 = col >> 3, ce = col & 7;
#pragma unroll
      for (int rg = 0; rg < 4; ++rg) {
        int row = row0 + rg;
        float v = acc[i][j][rg];
        v = v > 0.0f ? v : 0.0f;
        X[row * 256 + (((c8 ^ (row & 7)) << 3) | ce)] = f2bf(v);
      }
    }
  }
#pragma unroll
  for (int i = 0; i < 4; ++i)
#pragma unroll
    for (int j = 0; j < 4; ++j) acc[i][j] = (floatx4)(0.0f);
  __syncthreads();
#pragma unroll
  for (int k32 = 0; k32 < 8; ++k32) {
    short8 b[4], af[4];
#pragma unroll
    for (int jt = 0; jt < 4; ++jt)
      b[jt] = B2[(k32 * 256 + w * 64 + jt * 16 + lm) * 4 + lq];
#pragma unroll
    for (int i = 0; i < 4; ++i) {
      int r = i * 16 + lm, c = k32 * 4 + lq;
      af[i] = *(const short8*)&X[r * 256 + ((c ^ (r & 7)) << 3)];
    }
#pragma unroll
    for (int i = 0; i < 4; ++i)
#pragma unroll
      for (int j = 0; j < 4; ++j)
        acc[i][j] = __builtin_amdgcn_mfma_f32_16x16x32_bf16(af[i], b[j], acc[i][j], 0, 0, 0);
  }
  __syncthreads();
#pragma unroll
  for (int i = 0; i < 4; ++i) {
    int row0 = i * 16 + lq * 4;
#pragma unroll
    for (int j = 0; j < 4; ++j) {
      int col = w * 64 + j * 16 + lm, c8 = col >> 3, ce = col & 7;
#pragma unroll
      for (int rg = 0; rg < 4; ++rg) {
        int row = row0 + rg;
        float v = acc[i][j][rg];
        v = v > 0.0f ? v : 0.0f;
        X[row * 256 + (((c8 ^ (row & 7)) << 3) | ce)] = f2bf(v);
      }
    }
  }
  __syncthreads();
  {
    int r = t >> 2, o = (t >> 1) & 1, hh = t & 1;
    float s = 0.0f;
#pragma unroll
    for (int it = 0; it < 16; ++it) {
      int c = hh * 16 + it;
      short8 xv = *(const short8*)&X[r * 256 + ((c ^ (r & 7)) << 3)];
#pragma unroll
      for (int e = 0; e < 8; ++e)
        s += bf2f((unsigned short)xv[e]) * w3s[((c << 3) + e) * 2 + o];
    }
    s += __shfl_xor(s, 1);
    if (hh == 0) out[(m0 + r) * 2 + o] = s;
  }
}

extern "C" void kernel_launch(void* const* d_in, const int* in_sizes, int n_in,
                              void* d_out, int out_size, void* d_ws, size_t ws_size,
                              hipStream_t stream) {
  const float* h   = (const float*)d_in[0];
  const int*   dst = (const int*)d_in[1];
  const int*   src = (const int*)d_in[2];
  const float* W1  = (const float*)d_in[3];
  const float* W2  = (const float*)d_in[4];
  const float* W3  = (const float*)d_in[5];
  float* out = (float*)d_out;

  const int h_elems = in_sizes[0];
  const int n_pairs = in_sizes[1];
  const int ntiles  = n_pairs / 64;

  const size_t hbf_elems = (size_t)h_elems;
  const bool use_hbf =
      ws_size >= (hbf_elems + 131072 + 65536 + 4096) * sizeof(unsigned short);

  unsigned short* HBF = (unsigned short*)d_ws;
  unsigned short* W1F = HBF + hbf_elems;
  unsigned short* W2F = W1F + 131072;
  unsigned short* W3F = W2F + 65536;

  if (use_hbf) {
    int nh4 = h_elems / 4;
    int grid = 512 + 256 + 16 + (nh4 + 255) / 256;
    prep_kernel<<<grid, 256, 0, stream>>>(h, W1, W2, W3, HBF, W1F, W2F, W3F, nh4);
    int pgrid = ntiles < 256 ? ntiles : 256;   // persistent, 1 block/CU
    edge_mlp5<<<pgrid, 512, 0, stream>>>(HBF, dst, src, W1F, W2F, W3F, out, ntiles);
  } else {
    unsigned short* W1Fb = (unsigned short*)d_ws;
    unsigned short* W2Fb = W1Fb + 131072;
    wfrag_kernel<<<512, 256, 0, stream>>>(W1, W1Fb, 131072);
    wfrag_kernel<<<256, 256, 0, stream>>>(W2, W2Fb, 65536);
    edge_mlp_fb<<<ntiles, 256, 0, stream>>>(h, dst, src, W1Fb, W2Fb, W3, out);
  }
}

// Round 10
// 534.659 us; speedup vs baseline: 1.7266x; 1.7266x over previous
//
#include <hip/hip_runtime.h>
#include <stdint.h>

typedef __attribute__((ext_vector_type(8))) short short8;
typedef __attribute__((ext_vector_type(4))) short short4v;
typedef __attribute__((ext_vector_type(4))) float floatx4;

__device__ __forceinline__ unsigned short f2bf(float x) {
  unsigned int u = __float_as_uint(x);
  u += 0x7fffu + ((u >> 16) & 1u);   // RNE
  return (unsigned short)(u >> 16);
}
__device__ __forceinline__ float bf2f(unsigned short b) {
  return __uint_as_float(((unsigned int)b) << 16);
}
__device__ __forceinline__ int sw3(int r) { return (r & 7) ^ (((r >> 3) & 1) * 3); }

// ---- unified prologue: weight frags + h bf16 table (layouts as R7) ----
__global__ void prep_kernel(const float* __restrict__ h, const float* __restrict__ W1,
                            const float* __restrict__ W2, const float* __restrict__ W3,
                            unsigned short* __restrict__ HBF, unsigned short* __restrict__ W1F,
                            unsigned short* __restrict__ W2F, unsigned short* __restrict__ W3F,
                            int nh4) {
  const int t = threadIdx.x;
  int b = blockIdx.x;
  if (b < 512) {
    int u = b * 256 + t;
    int j = u & 7, kq = (u >> 3) & 3, n = (u >> 5) & 255, k32 = u >> 13;
    W1F[u] = f2bf(W1[(k32 * 32 + kq * 8 + j) * 256 + n]);
    return;
  }
  b -= 512;
  if (b < 256) {
    int u = b * 256 + t;
    int j = u & 7, kq = (u >> 3) & 3, n = (u >> 5) & 255, k32 = u >> 13;
    W2F[u] = f2bf(W2[(k32 * 32 + kq * 8 + j) * 256 + n]);
    return;
  }
  b -= 256;
  if (b < 16) {
    int u = b * 256 + t;
    int j = u & 7, L = (u >> 3) & 63, k32 = u >> 9;
    int n = L & 15, kq = L >> 4;
    W3F[u] = (n < 2) ? f2bf(W3[(k32 * 32 + kq * 8 + j) * 2 + n]) : (unsigned short)0;
    return;
  }
  b -= 16;
  int u = b * 256 + t;
  if (u < nh4) {
    float4 v = ((const float4*)h)[u];
    short4v s;
    s[0] = (short)f2bf(v.x); s[1] = (short)f2bf(v.y);
    s[2] = (short)f2bf(v.z); s[3] = (short)f2bf(v.w);
    ((short4v*)HBF)[u] = s;
  }
}

// ---- main kernel: M=32 tile, 33 KB LDS -> 4 blocks/CU (16 waves, 4/SIMD) ----
// Same verified mappings as R7, i-extent halved. VGPR diet keeps count <=128:
// acc 32 + B-ring(2) 32 + gather batch g[4] 16 + addr ~20.
// A: 32 pair-rows x 64 chunks x 16 B (swizzle slot=c^sw3(r)); X/X2 overlay A.
__global__ __launch_bounds__(256, 4)
void edge_mlp6(const unsigned short* __restrict__ hbf,
               const int* __restrict__ dst,
               const int* __restrict__ src,
               const unsigned short* __restrict__ W1F,
               const unsigned short* __restrict__ W2F,
               const unsigned short* __restrict__ W3F,
               float* __restrict__ out) {
  __shared__ unsigned short A[32 * 512];
  __shared__ int ioff[64];
  unsigned short* X  = A;              // [32][256] overlay
  unsigned short* X2 = A + 32 * 256;   // [32][256] overlay (upper 16 KB)

  const int t = threadIdx.x, lane = t & 63, w = t >> 6;
  const int lq = lane >> 4, lm = lane & 15;
  const int m0 = blockIdx.x * 32;

  if (t < 64) ioff[t] = (t < 32) ? dst[m0 + t] : src[m0 + t - 32];
  __syncthreads();

  // ---- Gather: 8 chunk-loads/thread in 2 batches of 4 (keeps VGPRs <=128)
  {
    const int c = lane, half = (c >= 32) ? 32 : 0, cc = c & 31;
#pragma unroll
    for (int bat = 0; bat < 2; ++bat) {
      short8 g[4];
#pragma unroll
      for (int it = 0; it < 4; ++it) {
        int r = (bat * 4 + it) * 4 + w;
        int node = ioff[half + r];
        g[it] = ((const short8*)hbf)[(size_t)node * 32 + cc];
      }
#pragma unroll
      for (int it = 0; it < 4; ++it) {
        int r = (bat * 4 + it) * 4 + w;
        *(short8*)&A[r * 512 + ((c ^ sw3(r)) << 3)] = g[it];
      }
    }
  }

  floatx4 acc[2][4];
#pragma unroll
  for (int i = 0; i < 2; ++i)
#pragma unroll
    for (int j = 0; j < 4; ++j) acc[i][j] = (floatx4)(0.0f);
  __syncthreads();

  const short8* B1 = (const short8*)W1F;
  const short8* B2 = (const short8*)W2F;
  const short8* B3 = (const short8*)W3F;

  // ---- Layer 1: K=512, 16 k-steps, B-ring depth 2
  {
    short8 bq[2][4];
#pragma unroll
    for (int s = 0; s < 2; ++s)
#pragma unroll
      for (int jt = 0; jt < 4; ++jt)
        bq[s][jt] = B1[(s * 256 + w * 64 + jt * 16 + lm) * 4 + lq];

#pragma unroll
    for (int s = 0; s < 16; ++s) {
#pragma unroll
      for (int i = 0; i < 2; ++i) {
        int r = i * 16 + lm, cch = s * 4 + lq;
        short8 af = *(const short8*)&A[r * 512 + ((cch ^ sw3(r)) << 3)];
#pragma unroll
        for (int j = 0; j < 4; ++j)
          acc[i][j] = __builtin_amdgcn_mfma_f32_16x16x32_bf16(af, bq[s & 1][j], acc[i][j], 0, 0, 0);
      }
      if (s < 14)
#pragma unroll
        for (int jt = 0; jt < 4; ++jt)
          bq[s & 1][jt] = B1[((s + 2) * 256 + w * 64 + jt * 16 + lm) * 4 + lq];
    }
  }
  __syncthreads();

  // ---- Epilogue 1: relu -> X (C/D: col=lane&15, row=quad*4+reg)
#pragma unroll
  for (int i = 0; i < 2; ++i) {
    int row0 = i * 16 + lq * 4;
#pragma unroll
    for (int j = 0; j < 4; ++j) {
      int col = w * 64 + j * 16 + lm, c8 = col >> 3, ce = col & 7;
#pragma unroll
      for (int rg = 0; rg < 4; ++rg) {
        int row = row0 + rg;
        float v = acc[i][j][rg];
        v = v > 0.0f ? v : 0.0f;
        X[row * 256 + (((c8 ^ sw3(row)) << 3) | ce)] = f2bf(v);
      }
    }
  }
#pragma unroll
  for (int i = 0; i < 2; ++i)
#pragma unroll
    for (int j = 0; j < 4; ++j) acc[i][j] = (floatx4)(0.0f);
  __syncthreads();

  // ---- Layer 2: K=256, 8 k-steps, B-ring depth 2
  {
    short8 bq[2][4];
#pragma unroll
    for (int s = 0; s < 2; ++s)
#pragma unroll
      for (int jt = 0; jt < 4; ++jt)
        bq[s][jt] = B2[(s * 256 + w * 64 + jt * 16 + lm) * 4 + lq];

#pragma unroll
    for (int s = 0; s < 8; ++s) {
#pragma unroll
      for (int i = 0; i < 2; ++i) {
        int r = i * 16 + lm, cch = s * 4 + lq;
        short8 af = *(const short8*)&X[r * 256 + ((cch ^ sw3(r)) << 3)];
#pragma unroll
        for (int j = 0; j < 4; ++j)
          acc[i][j] = __builtin_amdgcn_mfma_f32_16x16x32_bf16(af, bq[s & 1][j], acc[i][j], 0, 0, 0);
      }
      if (s < 6)
#pragma unroll
        for (int jt = 0; jt < 4; ++jt)
          bq[s & 1][jt] = B2[((s + 2) * 256 + w * 64 + jt * 16 + lm) * 4 + lq];
    }
  }
  __syncthreads();

  // ---- Epilogue 2: relu -> X2
#pragma unroll
  for (int i = 0; i < 2; ++i) {
    int row0 = i * 16 + lq * 4;
#pragma unroll
    for (int j = 0; j < 4; ++j) {
      int col = w * 64 + j * 16 + lm, c8 = col >> 3, ce = col & 7;
#pragma unroll
      for (int rg = 0; rg < 4; ++rg) {
        int row = row0 + rg;
        float v = acc[i][j][rg];
        v = v > 0.0f ? v : 0.0f;
        X2[row * 256 + (((c8 ^ sw3(row)) << 3) | ce)] = f2bf(v);
      }
    }
  }
  __syncthreads();

  // ---- Layer 3 (waves 0,1): X2 @ W3 via MFMA, N padded to 16
  if (w < 2) {
    floatx4 a3 = (floatx4)(0.0f);
#pragma unroll
    for (int s = 0; s < 8; ++s) {
      short8 b3 = B3[s * 64 + lane];
      int r = w * 16 + lm;
      short8 af = *(const short8*)&X2[r * 256 + (((s * 4 + lq) ^ sw3(r)) << 3)];
      a3 = __builtin_amdgcn_mfma_f32_16x16x32_bf16(af, b3, a3, 0, 0, 0);
    }
    if (lm < 2) {
#pragma unroll
      for (int rg = 0; rg < 4; ++rg)
        out[(m0 + w * 16 + lq * 4 + rg) * 2 + lm] = a3[rg];
    }
  }
}

// ---- legacy weight-frag kernel (fallback path only) ----
__global__ void wfrag_kernel(const float* __restrict__ W,
                             unsigned short* __restrict__ out, int total) {
  int u = blockIdx.x * 256 + threadIdx.x;
  if (u >= total) return;
  int j = u & 7, kq = (u >> 3) & 3, n = (u >> 5) & 255, k32 = u >> 13;
  out[u] = f2bf(W[(k32 * 32 + kq * 8 + j) * 256 + n]);
}

// ---- fp32-gather fallback (tiny workspace) ----
__global__ __launch_bounds__(256, 2)
void edge_mlp_fb(const float* __restrict__ h,
                 const int* __restrict__ dst,
                 const int* __restrict__ src,
                 const unsigned short* __restrict__ W1F,
                 const unsigned short* __restrict__ W2F,
                 const float* __restrict__ W3,
                 float* __restrict__ out) {
  __shared__ unsigned short A[64 * 512];
  __shared__ float w3s[512];
  __shared__ int ioff[128];
  unsigned short* X = A;
  const int t = threadIdx.x, lane = t & 63, w = t >> 6;
  const int lq = lane >> 4, lm = lane & 15;
  const int m0 = blockIdx.x * 64;
  if (t < 64) ioff[t] = dst[m0 + t];
  else if (t < 128) ioff[t] = src[m0 + t - 64];
  w3s[t] = W3[t];
  w3s[t + 256] = W3[t + 256];
  __syncthreads();
  {
    const int c = lane, half = (c >= 32) ? 64 : 0, cc = c & 31;
#pragma unroll
    for (int it = 0; it < 16; ++it) {
      int r = it * 4 + w;
      int node = ioff[half + r];
      const float4* h4 = (const float4*)h;
      float4 v0 = h4[node * 64 + cc * 2], v1 = h4[node * 64 + cc * 2 + 1];
      short8 v;
      v[0] = (short)f2bf(v0.x); v[1] = (short)f2bf(v0.y);
      v[2] = (short)f2bf(v0.z); v[3] = (short)f2bf(v0.w);
      v[4] = (short)f2bf(v1.x); v[5] = (short)f2bf(v1.y);
      v[6] = (short)f2bf(v1.z); v[7] = (short)f2bf(v1.w);
      *(short8*)&A[r * 512 + ((c ^ (r & 7)) << 3)] = v;
    }
  }
  floatx4 acc[4][4];
#pragma unroll
  for (int i = 0; i < 4; ++i)
#pragma unroll
    for (int j = 0; j < 4; ++j) acc[i][j] = (floatx4)(0.0f);
  __syncthreads();
  const short8* B1 = (const short8*)W1F;
  const short8* B2 = (const short8*)W2F;
#pragma unroll
  for (int k32 = 0; k32 < 16; ++k32) {
    short8 b[4], af[4];
#pragma unroll
    for (int jt = 0; jt < 4; ++jt)
      b[jt] = B1[(k32 * 256 + w * 64 + jt * 16 + lm) * 4 + lq];
#pragma unroll
    for (int i = 0; i < 4; ++i) {
      int r = i * 16 + lm, c = k32 * 4 + lq;
      af[i] = *(const short8*)&A[r * 512 + ((c ^ (r & 7)) << 3)];
    }
#pragma unroll
    for (int i = 0; i < 4; ++i)
#pragma unroll
      for (int j = 0; j < 4; ++j)
        acc[i][j] = __builtin_amdgcn_mfma_f32_16x16x32_bf16(af[i], b[j], acc[i][j], 0, 0, 0);
  }
  __syncthreads();
#pragma unroll
  for (int i = 0; i < 4; ++i) {
    int row0 = i * 16 + lq * 4;
#pragma unroll
    for (int j = 0; j < 4; ++j) {
      int col = w * 64 + j * 16 + lm, c8 = col >> 3, ce = col & 7;
#pragma unroll
      for (int rg = 0; rg < 4; ++rg) {
        int row = row0 + rg;
        float v = acc[i][j][rg];
        v = v > 0.0f ? v : 0.0f;
        X[row * 256 + (((c8 ^ (row & 7)) << 3) | ce)] = f2bf(v);
      }
    }
  }
#pragma unroll
  for (int i = 0; i < 4; ++i)
#pragma unroll
    for (int j = 0; j < 4; ++j) acc[i][j] = (floatx4)(0.0f);
  __syncthreads();
#pragma unroll
  for (int k32 = 0; k32 < 8; ++k32) {
    short8 b[4], af[4];
#pragma unroll
    for (int jt = 0; jt < 4; ++jt)
      b[jt] = B2[(k32 * 256 + w * 64 + jt * 16 + lm) * 4 + lq];
#pragma unroll
    for (int i = 0; i < 4; ++i) {
      int r = i * 16 + lm, c = k32 * 4 + lq;
      af[i] = *(const short8*)&X[r * 256 + ((c ^ (r & 7)) << 3)];
    }
#pragma unroll
    for (int i = 0; i < 4; ++i)
#pragma unroll
      for (int j = 0; j < 4; ++j)
        acc[i][j] = __builtin_amdgcn_mfma_f32_16x16x32_bf16(af[i], b[j], acc[i][j], 0, 0, 0);
  }
  __syncthreads();
#pragma unroll
  for (int i = 0; i < 4; ++i) {
    int row0 = i * 16 + lq * 4;
#pragma unroll
    for (int j = 0; j < 4; ++j) {
      int col = w * 64 + j * 16 + lm, c8 = col >> 3, ce = col & 7;
#pragma unroll
      for (int rg = 0; rg < 4; ++rg) {
        int row = row0 + rg;
        float v = acc[i][j][rg];
        v = v > 0.0f ? v : 0.0f;
        X[row * 256 + (((c8 ^ (row & 7)) << 3) | ce)] = f2bf(v);
      }
    }
  }
  __syncthreads();
  {
    int r = t >> 2, o = (t >> 1) & 1, hh = t & 1;
    float s = 0.0f;
#pragma unroll
    for (int it = 0; it < 16; ++it) {
      int c = hh * 16 + it;
      short8 xv = *(const short8*)&X[r * 256 + ((c ^ (r & 7)) << 3)];
#pragma unroll
      for (int e = 0; e < 8; ++e)
        s += bf2f((unsigned short)xv[e]) * w3s[((c << 3) + e) * 2 + o];
    }
    s += __shfl_xor(s, 1);
    if (hh == 0) out[(m0 + r) * 2 + o] = s;
  }
}

extern "C" void kernel_launch(void* const* d_in, const int* in_sizes, int n_in,
                              void* d_out, int out_size, void* d_ws, size_t ws_size,
                              hipStream_t stream) {
  const float* h   = (const float*)d_in[0];
  const int*   dst = (const int*)d_in[1];
  const int*   src = (const int*)d_in[2];
  const float* W1  = (const float*)d_in[3];
  const float* W2  = (const float*)d_in[4];
  const float* W3  = (const float*)d_in[5];
  float* out = (float*)d_out;

  const int h_elems = in_sizes[0];
  const int n_pairs = in_sizes[1];

  const size_t hbf_elems = (size_t)h_elems;
  const bool use_hbf =
      ws_size >= (hbf_elems + 131072 + 65536 + 4096) * sizeof(unsigned short);

  unsigned short* HBF = (unsigned short*)d_ws;
  unsigned short* W1F = HBF + hbf_elems;
  unsigned short* W2F = W1F + 131072;
  unsigned short* W3F = W2F + 65536;

  if (use_hbf) {
    int nh4 = h_elems / 4;
    int grid = 512 + 256 + 16 + (nh4 + 255) / 256;
    prep_kernel<<<grid, 256, 0, stream>>>(h, W1, W2, W3, HBF, W1F, W2F, W3F, nh4);
    edge_mlp6<<<n_pairs / 32, 256, 0, stream>>>(HBF, dst, src, W1F, W2F, W3F, out);
  } else {
    unsigned short* W1Fb = (unsigned short*)d_ws;
    unsigned short* W2Fb = W1Fb + 131072;
    wfrag_kernel<<<512, 256, 0, stream>>>(W1, W1Fb, 131072);
    wfrag_kernel<<<256, 256, 0, stream>>>(W2, W2Fb, 65536);
    edge_mlp_fb<<<n_pairs / 64, 256, 0, stream>>>(h, dst, src, W1Fb, W2Fb, W3, out);
  }
}